// Round 1
// 477.913 us; speedup vs baseline: 1.1255x; 1.1255x over previous
//
#include <hip/hip_runtime.h>
#include <stdint.h>

constexpr int NROWS = 1000000;
constexpr int D = 64;
constexpr int B = 64;
constexpr int TOPK = 5;
constexpr int TBLK = 8;      // per-block per-batch candidates kept
constexpr int TRES = 16;     // globally rescored candidates per batch
constexpr int NB2MAX = 1280; // 5 blocks/CU, fully resident

typedef __attribute__((ext_vector_type(8))) short short8;
typedef __attribute__((ext_vector_type(4))) float floatx4;

// workspace byte offsets
#define OFF_QKF   512      // qkf[64*64] f32   (16 KB)
#define OFF_QKB   16896    // qkb[64*64] bf16  (8 KB)
#define OFF_MM    25088    // minmax partials nb2*2 u32 (<= 32 KB)
#define OFF_CAND  57856    // cand[nb2*64*TBLK] u64

__device__ __forceinline__ unsigned fkey(float x) {
    unsigned u = __float_as_uint(x);
    return (u & 0x80000000u) ? ~u : (u | 0x80000000u);
}
__device__ __forceinline__ float fkey_inv(unsigned k) {
    unsigned u = (k & 0x80000000u) ? (k ^ 0x80000000u) : ~k;
    return __uint_as_float(u);
}
__device__ __forceinline__ unsigned short f2bf_rne(float x) {
    unsigned u = __float_as_uint(x);
    u += 0x7fffu + ((u >> 16) & 1u);
    return (unsigned short)(u >> 16);
}

template<int K>
__device__ __forceinline__ void insert_key(unsigned long long (&ks)[K],
                                           unsigned long long key) {
    if (key > ks[K - 1]) {
        #pragma unroll
        for (int j = K - 1; j > 0; --j)
            ks[j] = (key > ks[j - 1]) ? ks[j - 1] : ((key > ks[j]) ? key : ks[j]);
        ks[0] = (key > ks[0]) ? key : ks[0];
    }
}

// 16 blocks, 4 batches each: q = query@Wq^T, qk = q@Wk * 0.125.
// No min/max dependency anymore: scoring is done against raw bf16 memory,
// so emit fp32 qk (exact rescore) and bf16 qk (MFMA B operand) directly.
__global__ void k_qk(const float* __restrict__ query, const float* __restrict__ Wq,
                     const float* __restrict__ Wk,
                     float* __restrict__ qkf, unsigned short* __restrict__ qkb) {
    __shared__ float q[4][64];
    int t = threadIdx.x;
    int b0 = blockIdx.x * 4;
    int bq = t >> 6, d = t & 63;
    float s1 = 0.f;
    for (int e = 0; e < 64; e++) s1 += query[(b0 + bq) * 64 + e] * Wq[d * 64 + e];
    q[bq][d] = s1;
    __syncthreads();
    float v = 0.f;
    for (int dd = 0; dd < 64; dd++) v += q[bq][dd] * Wk[dd * 64 + d];
    v *= 0.125f;
    qkf[(b0 + bq) * 64 + d] = v;
    qkb[(b0 + bq) * 64 + d] = f2bf_rne(v);
}

// Fused single pass over memory: bf16-convert tile for MFMA scoring AND
// accumulate global min/max partials (scale/zp are only needed later, for the
// exact rescore of 16 candidates in k_finalize). Register-prefetch pipeline
// with raw barriers (no vmcnt drain -> prefetch overlaps compute).
__launch_bounds__(256, 5)
__global__ void k_score_mm(const float* __restrict__ mem, const float* __restrict__ aw,
                           const unsigned short* __restrict__ qkb,
                           unsigned long long* __restrict__ cand,
                           unsigned* __restrict__ part, int rowsPerBlock) {
    // codes[64][72] ushort (9216 B) + scores[64][68] f32 (17408 B) overlaid with
    // cmerge[256*TBLK] u64 (16384 B) -> 26624 B
    __shared__ __align__(16) char smem[26624];
    __shared__ float awt[64];
    __shared__ float swmn[4], swmx[4];
    unsigned short (*codes)[72] = (unsigned short (*)[72])smem;
    float (*scores)[68] = (float (*)[68])(smem + 9216);
    unsigned long long* cmerge = (unsigned long long*)smem;

    int t = threadIdx.x;
    int l15 = t & 15, quad = (t >> 4) & 3, w = t >> 6;
    int b = t & 63;

    // B fragments: B[k=quad*8+j][n=l15] from qkb[b][d]
    short8 bq[4][2];
    #pragma unroll
    for (int bt = 0; bt < 4; bt++) {
        #pragma unroll
        for (int kb = 0; kb < 2; kb++)
            bq[bt][kb] = *(const short8*)(qkb + (bt * 16 + l15) * 64 + kb * 32 + quad * 8);
    }

    unsigned long long ks[TBLK];
    #pragma unroll
    for (int j = 0; j < TBLK; j++) ks[j] = 0ull;

    float mnv = 3.402823466e38f, mxv = -3.402823466e38f;

    int row0 = blockIdx.x * rowsPerBlock;
    int rowEnd = min(row0 + rowsPerBlock, NROWS);

    // prologue prefetch: tile 0 into registers
    float4 pre[4];
    float preaw = 0.f;
    {
        int base = row0 < NROWS ? row0 : 0;
        #pragma unroll
        for (int i = 0; i < 4; i++) {
            int flat = (i * 256 + t) * 4;
            int g = base * 64 + flat;
            if (g > NROWS * 64 - 4) g = NROWS * 64 - 4;
            pre[i] = *(const float4*)(mem + g);
        }
        if (t < 64) {
            int ai = base + t; if (ai > NROWS - 1) ai = NROWS - 1;
            preaw = aw[ai];
        }
    }

    for (int base = row0; base < rowEnd; base += 64) {
        // bf16-convert prefetched tile + min/max accumulate
        #pragma unroll
        for (int i = 0; i < 4; i++) {
            float4 v = pre[i];
            mnv = fminf(mnv, fminf(fminf(v.x, v.y), fminf(v.z, v.w)));
            mxv = fmaxf(mxv, fmaxf(fmaxf(v.x, v.y), fmaxf(v.z, v.w)));
            ushort4 c;
            c.x = f2bf_rne(v.x);
            c.y = f2bf_rne(v.y);
            c.z = f2bf_rne(v.z);
            c.w = f2bf_rne(v.w);
            int flat = (i * 256 + t) * 4;
            *(ushort4*)&codes[flat >> 6][flat & 63] = c;
        }
        if (t < 64) awt[t] = preaw;

        // issue prefetch for next tile (stays in flight across raw barriers)
        int nbase = (base + 64 < rowEnd) ? base + 64 : base;
        #pragma unroll
        for (int i = 0; i < 4; i++) {
            int flat = (i * 256 + t) * 4;
            int g = nbase * 64 + flat;
            if (g > NROWS * 64 - 4) g = NROWS * 64 - 4;
            pre[i] = *(const float4*)(mem + g);
        }
        if (t < 64) {
            int ai = nbase + t; if (ai > NROWS - 1) ai = NROWS - 1;
            preaw = aw[ai];
        }

        asm volatile("s_waitcnt lgkmcnt(0)" ::: "memory");
        __builtin_amdgcn_s_barrier();   // codes tile visible to all waves

        // A fragments: rows w*16 + l15
        short8 a0 = *(const short8*)&codes[w * 16 + l15][quad * 8];
        short8 a1 = *(const short8*)&codes[w * 16 + l15][32 + quad * 8];
        float aw4[4];
        #pragma unroll
        for (int r = 0; r < 4; r++) aw4[r] = awt[w * 16 + quad * 4 + r];

        #pragma unroll
        for (int bt = 0; bt < 4; bt++) {
            floatx4 acc = {aw4[0], aw4[1], aw4[2], aw4[3]};
            acc = __builtin_amdgcn_mfma_f32_16x16x32_bf16(a0, bq[bt][0], acc, 0, 0, 0);
            acc = __builtin_amdgcn_mfma_f32_16x16x32_bf16(a1, bq[bt][1], acc, 0, 0, 0);
            *(floatx4*)&scores[bt * 16 + l15][w * 16 + quad * 4] = acc;
        }

        // scan rows [w*16, w*16+16) of this thread's batch (written by own wave)
        #pragma unroll
        for (int j = 0; j < 4; j++) {
            floatx4 v = *(const floatx4*)&scores[b][w * 16 + 4 * j];
            #pragma unroll
            for (int c2 = 0; c2 < 4; c2++) {
                int gr = base + w * 16 + 4 * j + c2;
                if (gr < rowEnd) {
                    unsigned long long key =
                        ((unsigned long long)fkey(v[c2]) << 32) | (unsigned)(~(unsigned)gr);
                    insert_key<TBLK>(ks, key);
                }
            }
        }

        asm volatile("s_waitcnt lgkmcnt(0)" ::: "memory");
        __builtin_amdgcn_s_barrier();   // tile fully consumed
    }

    // min/max: wave reduce, stage per-wave partials
    float mnw = mnv, mxw = mxv;
    #pragma unroll
    for (int o = 32; o > 0; o >>= 1) {
        mnw = fminf(mnw, __shfl_xor(mnw, o));
        mxw = fmaxf(mxw, __shfl_xor(mxw, o));
    }
    if ((t & 63) == 0) { swmn[w] = mnw; swmx[w] = mxw; }

    __syncthreads();
    #pragma unroll
    for (int j = 0; j < TBLK; j++) cmerge[t * TBLK + j] = ks[j];
    __syncthreads();
    if (t == 0) {
        float a = fminf(fminf(swmn[0], swmn[1]), fminf(swmn[2], swmn[3]));
        float b2 = fmaxf(fmaxf(swmx[0], swmx[1]), fmaxf(swmx[2], swmx[3]));
        part[blockIdx.x * 2 + 0] = fkey(a);
        part[blockIdx.x * 2 + 1] = fkey(b2);
    }
    if (t < 64) {
        unsigned long long ts[TBLK];
        #pragma unroll
        for (int j = 0; j < TBLK; j++) ts[j] = 0ull;
        for (int ww = 0; ww < 4; ww++)
            #pragma unroll
            for (int j = 0; j < TBLK; j++)
                insert_key<TBLK>(ts, cmerge[(ww * 64 + t) * TBLK + j]);
        #pragma unroll
        for (int j = 0; j < TBLK; j++)
            cand[((long long)blockIdx.x * 64 + t) * TBLK + j] = ts[j];
    }
}

// One block per batch: reduce min/max partials -> scale/zp (overlapped with
// candidate gather), per-thread gated top-16 over strided candidates,
// 8-level pairwise sorted-merge tree, exact fp32 rescore of top-16, top-5,
// softmax, weighted dequant row sum, @ Wv^T.
__global__ void k_finalize(const unsigned long long* __restrict__ cand, int nb2,
                           const float* __restrict__ mem, const float* __restrict__ aw,
                           const float* __restrict__ Wv, const unsigned* __restrict__ part,
                           const float* __restrict__ qkf, float* __restrict__ out) {
    __shared__ unsigned long long lists[256][TRES];   // 32 KB
    __shared__ float qkr[64];
    __shared__ int exid[TRES];
    __shared__ unsigned long long exkey[TRES];
    __shared__ float exsc[TRES];
    __shared__ float wsel[TOPK];
    __shared__ int isel[TOPK];
    __shared__ float su[64];
    __shared__ unsigned redmn[4], redmx[4];
    __shared__ float sscale[2];

    int t = threadIdx.x, b = blockIdx.x;
    int total = nb2 * TBLK;

    // min/max partial reduction (independent of candidate gather)
    unsigned mnk = 0xFFFFFFFFu, mxk = 0u;
    for (int i = t; i < nb2; i += 256) {
        unsigned a = part[2 * i], c = part[2 * i + 1];
        mnk = a < mnk ? a : mnk;
        mxk = c > mxk ? c : mxk;
    }
    #pragma unroll
    for (int o = 32; o > 0; o >>= 1) {
        unsigned am = __shfl_xor(mnk, o); mnk = am < mnk ? am : mnk;
        unsigned ax = __shfl_xor(mxk, o); mxk = ax > mxk ? ax : mxk;
    }
    int w4 = t >> 6;
    if ((t & 63) == 0) { redmn[w4] = mnk; redmx[w4] = mxk; }

    unsigned long long loc[TRES];
    #pragma unroll
    for (int j = 0; j < TRES; j++) loc[j] = 0ull;
    for (int i = t; i < total; i += 256) {
        int blk = i / TBLK, j = i - blk * TBLK;
        insert_key<TRES>(loc, cand[((long long)blk * 64 + b) * TBLK + j]);
    }
    #pragma unroll
    for (int j = 0; j < TRES; j++) lists[t][j] = loc[j];
    if (t < 64) qkr[t] = qkf[b * 64 + t];
    __syncthreads();

    // idle thread (not in first tree level) finalizes scale/zp
    if (t == 255) {
        unsigned m0 = redmn[0], M0 = redmx[0];
        #pragma unroll
        for (int i = 1; i < 4; i++) {
            m0 = redmn[i] < m0 ? redmn[i] : m0;
            M0 = redmx[i] > M0 ? redmx[i] : M0;
        }
        float mnv = fkey_inv(m0), mxv = fkey_inv(M0);
        float scale = (mxv - mnv) / 255.0f;
        sscale[0] = scale;
        sscale[1] = -mnv / scale;
    }

    for (int s = 128; s > 0; s >>= 1) {
        if (t < s) {
            #pragma unroll
            for (int j = 0; j < TRES; j++) insert_key<TRES>(loc, lists[t + s][j]);
            #pragma unroll
            for (int j = 0; j < TRES; j++) lists[t][j] = loc[j];
        }
        __syncthreads();
    }
    if (t < TRES) {
        unsigned long long k = lists[0][t];
        exid[t] = k ? (int)(~(unsigned)k) : 0;
    }
    __syncthreads();

    float scale = sscale[0], zp = sscale[1];

    // exact rescore (mirrors reference: divide, rint, fp32)
    int lane = t & 63, w = t >> 6;
    for (int i = 0; i < 4; i++) {
        int c = w * 4 + i;
        int idx = exid[c];
        float m = mem[(long long)idx * 64 + lane];
        float dq = (rintf(m / scale + zp) - zp) * scale;
        float p2 = dq * qkr[lane];
        for (int o = 32; o > 0; o >>= 1) p2 += __shfl_xor(p2, o);
        if (lane == 0) {
            float ex = p2 + aw[idx];
            exsc[c] = ex;
            exkey[c] = ((unsigned long long)fkey(ex) << 32) | (unsigned)(~(unsigned)idx);
        }
    }
    __syncthreads();

    if (t == 0) {
        unsigned long long bnd = ~0ull;
        float ssel[TOPK];
        for (int p = 0; p < TOPK; p++) {
            unsigned long long best = 0ull; int bc = 0;
            for (int c = 0; c < TRES; c++) {
                unsigned long long k = exkey[c];
                if (k < bnd && k > best) { best = k; bc = c; }
            }
            bnd = best;
            ssel[p] = exsc[bc];
            isel[p] = exid[bc];
        }
        float Z = 0.f;
        for (int p = 0; p < TOPK; p++) { wsel[p] = expf(ssel[p] - ssel[0]); Z += wsel[p]; }
        for (int p = 0; p < TOPK; p++) wsel[p] /= Z;
    }
    __syncthreads();

    if (t < 64) {
        float u = 0.f;
        #pragma unroll
        for (int p = 0; p < TOPK; p++) {
            float m = mem[(long long)isel[p] * 64 + t];
            float dq = (rintf(m / scale + zp) - zp) * scale;
            u += wsel[p] * dq;
        }
        su[t] = u;
    }
    __syncthreads();
    if (t < 64) {
        float o = 0.f;
        #pragma unroll
        for (int e = 0; e < 64; e++) o += su[e] * Wv[t * 64 + e];
        out[b * 64 + t] = o;
    }
}

extern "C" void kernel_launch(void* const* d_in, const int* in_sizes, int n_in,
                              void* d_out, int out_size, void* d_ws, size_t ws_size,
                              hipStream_t stream) {
    const float* query = (const float*)d_in[0];
    const float* mem   = (const float*)d_in[1];
    const float* aw    = (const float*)d_in[2];
    const float* Wq    = (const float*)d_in[3];
    const float* Wk    = (const float*)d_in[4];
    const float* Wv    = (const float*)d_in[5];
    float* out = (float*)d_out;

    char* ws = (char*)d_ws;
    float* qkf     = (float*)(ws + OFF_QKF);
    unsigned short* qkb = (unsigned short*)(ws + OFF_QKB);
    unsigned* part = (unsigned*)(ws + OFF_MM);
    unsigned long long* cand = (unsigned long long*)(ws + OFF_CAND);

    int nb2 = NB2MAX;
    size_t need = (size_t)OFF_CAND + (size_t)nb2 * 64 * TBLK * 8;
    if (ws_size < need) {
        size_t avail = ws_size > OFF_CAND ? ws_size - OFF_CAND : 0;
        nb2 = (int)(avail / ((size_t)64 * TBLK * 8));
        if (nb2 < 8) nb2 = 8;
        if (nb2 > NB2MAX) nb2 = NB2MAX;
    }
    int rpb = (NROWS + nb2 - 1) / nb2;

    k_qk<<<16, 256, 0, stream>>>(query, Wq, Wk, qkf, qkb);
    k_score_mm<<<nb2, 256, 0, stream>>>(mem, aw, qkb, cand, part, rpb);
    k_finalize<<<B, 256, 0, stream>>>(cand, nb2, mem, aw, Wv, part, qkf, out);
}

// Round 2
// 415.083 us; speedup vs baseline: 1.2958x; 1.1514x over previous
//
#include <hip/hip_runtime.h>
#include <stdint.h>

constexpr int NROWS = 1000000;
constexpr int D = 64;
constexpr int B = 64;
constexpr int TOPK = 5;
constexpr int TBLK = 4;      // per-block per-batch candidates kept
constexpr int TRES = 16;     // globally rescored candidates per batch
constexpr int NB2MAX = 1024; // 4 blocks/CU, one resident round

typedef __attribute__((ext_vector_type(8))) short short8;
typedef __attribute__((ext_vector_type(4))) float floatx4;
typedef unsigned long long u64;

// workspace byte offsets
#define OFF_QKF   512      // qkf[64*64] f32   (16 KB)
#define OFF_QKB   16896    // qkb[64*64] bf16  (8 KB)
#define OFF_MM    25088    // minmax partials nb2*2 u32 (<= 32 KB)
#define OFF_CAND  57856    // cand[nb2*64*TBLK] u64

__device__ __forceinline__ unsigned fkey(float x) {
    unsigned u = __float_as_uint(x);
    return (u & 0x80000000u) ? ~u : (u | 0x80000000u);
}
__device__ __forceinline__ float fkey_inv(unsigned k) {
    unsigned u = (k & 0x80000000u) ? (k ^ 0x80000000u) : ~k;
    return __uint_as_float(u);
}
__device__ __forceinline__ unsigned short f2bf_rne(float x) {
    unsigned u = __float_as_uint(x);
    u += 0x7fffu + ((u >> 16) & 1u);
    return (unsigned short)(u >> 16);
}

template<int K>
__device__ __forceinline__ void insert_key(u64 (&ks)[K], u64 key) {
    if (key > ks[K - 1]) {
        #pragma unroll
        for (int j = K - 1; j > 0; --j)
            ks[j] = (key > ks[j - 1]) ? ks[j - 1] : ((key > ks[j]) ? key : ks[j]);
        ks[0] = (key > ks[0]) ? key : ks[0];
    }
}

// branchless top-2 insert: a >= b invariant
__device__ __forceinline__ void insert2(u64& a, u64& b, u64 key) {
    u64 hi = key > a ? key : a;
    u64 lo = key > a ? a : key;
    b = lo > b ? lo : b;
    a = hi;
}

// 16 blocks, 4 batches each: q = query@Wq^T, qk = q@Wk * 0.125.
__global__ void k_qk(const float* __restrict__ query, const float* __restrict__ Wq,
                     const float* __restrict__ Wk,
                     float* __restrict__ qkf, unsigned short* __restrict__ qkb) {
    __shared__ float q[4][64];
    int t = threadIdx.x;
    int b0 = blockIdx.x * 4;
    int bq = t >> 6, d = t & 63;
    float s1 = 0.f;
    for (int e = 0; e < 64; e++) s1 += query[(b0 + bq) * 64 + e] * Wq[d * 64 + e];
    q[bq][d] = s1;
    __syncthreads();
    float v = 0.f;
    for (int dd = 0; dd < 64; dd++) v += q[bq][dd] * Wk[dd * 64 + d];
    v *= 0.125f;
    qkf[(b0 + bq) * 64 + d] = v;
    qkb[(b0 + bq) * 64 + d] = f2bf_rne(v);
}

// Barrier-free scoring: each wave owns independent 16-row tiles. MFMA A-fragments
// are loaded directly from global in fragment layout (lane(quad,l15): row l15,
// d=quad*8..+7 and +32), converted to bf16 in-register. No LDS in the main loop.
// Candidate scan is in registers (branchless depth-2 per batch-tile), merged via
// shfl butterfly across quads, then a one-time 4 KB LDS merge across waves.
// min/max accumulated on the fly.
__launch_bounds__(256, 4)
__global__ void k_score_mm(const float* __restrict__ mem, const float* __restrict__ aw,
                           const unsigned short* __restrict__ qkb,
                           u64* __restrict__ cand,
                           unsigned* __restrict__ part, int wrows) {
    __shared__ u64 mrg[4][4][16][2];   // [wave][bt][l15][2] = 4 KB
    __shared__ float swmn[4], swmx[4];

    int t = threadIdx.x;
    int l15 = t & 15, quad = (t >> 4) & 3, w = t >> 6;

    // B fragments: B[k=quad*8+j][n=l15] from qkb[b][d]
    short8 bq[4][2];
    #pragma unroll
    for (int bt = 0; bt < 4; bt++) {
        #pragma unroll
        for (int kb = 0; kb < 2; kb++)
            bq[bt][kb] = *(const short8*)(qkb + (bt * 16 + l15) * 64 + kb * 32 + quad * 8);
    }

    u64 Ltop[4], Lsec[4];
    #pragma unroll
    for (int bt = 0; bt < 4; bt++) { Ltop[bt] = 0ull; Lsec[bt] = 0ull; }

    float mnv = 3.402823466e38f, mxv = -3.402823466e38f;

    int gw = blockIdx.x * 4 + w;
    int wbeg = gw * wrows;
    int wend = min(wbeg + wrows, NROWS);
    int span = wend - wbeg;
    int nt = span > 0 ? (span >> 4) : 0;   // ranges are exact multiples of 16

    const char* pbase = (const char*)mem + (size_t)wbeg * 256 + (size_t)(l15 * 256 + quad * 32);
    const float* abase = aw + wbeg + quad * 4;

    float4 p0, p1, p2, p3, pa;
    if (nt > 0) {
        p0 = *(const float4*)(pbase);
        p1 = *(const float4*)(pbase + 16);
        p2 = *(const float4*)(pbase + 128);
        p3 = *(const float4*)(pbase + 144);
        pa = *(const float4*)(abase);
    }

    for (int it = 0; it < nt; ++it) {
        // consume current tile (vmcnt wait auto-inserted at first use)
        float4 c0 = p0, c1 = p1, c2 = p2, c3 = p3;
        float aw0 = pa.x, aw1 = pa.y, aw2 = pa.z, aw3 = pa.w;

        // issue next-tile prefetch (clamped index re-reads last tile: harmless)
        int nx = (it + 1 < nt) ? (it + 1) : (nt - 1);
        const char* pn = pbase + (size_t)nx * 4096;
        p0 = *(const float4*)(pn);
        p1 = *(const float4*)(pn + 16);
        p2 = *(const float4*)(pn + 128);
        p3 = *(const float4*)(pn + 144);
        pa = *(const float4*)(abase + nx * 16);

        // min/max (nested for min3/max3 fusion)
        mnv = fminf(mnv, fminf(fminf(c0.x, c0.y), fminf(c0.z, c0.w)));
        mxv = fmaxf(mxv, fmaxf(fmaxf(c0.x, c0.y), fmaxf(c0.z, c0.w)));
        mnv = fminf(mnv, fminf(fminf(c1.x, c1.y), fminf(c1.z, c1.w)));
        mxv = fmaxf(mxv, fmaxf(fmaxf(c1.x, c1.y), fmaxf(c1.z, c1.w)));
        mnv = fminf(mnv, fminf(fminf(c2.x, c2.y), fminf(c2.z, c2.w)));
        mxv = fmaxf(mxv, fmaxf(fmaxf(c2.x, c2.y), fmaxf(c2.z, c2.w)));
        mnv = fminf(mnv, fminf(fminf(c3.x, c3.y), fminf(c3.z, c3.w)));
        mxv = fmaxf(mxv, fmaxf(fmaxf(c3.x, c3.y), fmaxf(c3.z, c3.w)));

        // bf16 A fragments in-register
        short8 a0, a1;
        a0[0] = (short)f2bf_rne(c0.x); a0[1] = (short)f2bf_rne(c0.y);
        a0[2] = (short)f2bf_rne(c0.z); a0[3] = (short)f2bf_rne(c0.w);
        a0[4] = (short)f2bf_rne(c1.x); a0[5] = (short)f2bf_rne(c1.y);
        a0[6] = (short)f2bf_rne(c1.z); a0[7] = (short)f2bf_rne(c1.w);
        a1[0] = (short)f2bf_rne(c2.x); a1[1] = (short)f2bf_rne(c2.y);
        a1[2] = (short)f2bf_rne(c2.z); a1[3] = (short)f2bf_rne(c2.w);
        a1[4] = (short)f2bf_rne(c3.x); a1[5] = (short)f2bf_rne(c3.y);
        a1[6] = (short)f2bf_rne(c3.z); a1[7] = (short)f2bf_rne(c3.w);

        int gr = wbeg + it * 16 + quad * 4;

        #pragma unroll
        for (int bt = 0; bt < 4; bt++) {
            floatx4 acc = {aw0, aw1, aw2, aw3};
            acc = __builtin_amdgcn_mfma_f32_16x16x32_bf16(a0, bq[bt][0], acc, 0, 0, 0);
            acc = __builtin_amdgcn_mfma_f32_16x16x32_bf16(a1, bq[bt][1], acc, 0, 0, 0);
            #pragma unroll
            for (int r = 0; r < 4; r++) {
                u64 key = ((u64)fkey(acc[r]) << 32) | (unsigned)(~(unsigned)(gr + r));
                insert2(Ltop[bt], Lsec[bt], key);
            }
        }
    }

    // wave-level min/max reduce
    #pragma unroll
    for (int o = 32; o > 0; o >>= 1) {
        mnv = fminf(mnv, __shfl_xor(mnv, o));
        mxv = fmaxf(mxv, __shfl_xor(mxv, o));
    }
    if ((t & 63) == 0) { swmn[w] = mnv; swmx[w] = mxv; }

    // butterfly merge across quads: each (bt,l15) ends with wave-top-2
    #pragma unroll
    for (int bt = 0; bt < 4; bt++) {
        #pragma unroll
        for (int dlt = 16; dlt <= 32; dlt <<= 1) {
            u64 ka = __shfl_xor(Ltop[bt], dlt);
            u64 kb = __shfl_xor(Lsec[bt], dlt);
            insert2(Ltop[bt], Lsec[bt], ka);
            insert2(Ltop[bt], Lsec[bt], kb);
        }
    }
    if ((t & 48) == 0) {
        #pragma unroll
        for (int bt = 0; bt < 4; bt++) {
            mrg[w][bt][l15][0] = Ltop[bt];
            mrg[w][bt][l15][1] = Lsec[bt];
        }
    }
    __syncthreads();

    if (t == 0) {
        float a = fminf(fminf(swmn[0], swmn[1]), fminf(swmn[2], swmn[3]));
        float b2 = fmaxf(fmaxf(swmx[0], swmx[1]), fmaxf(swmx[2], swmx[3]));
        part[blockIdx.x * 2 + 0] = fkey(a);
        part[blockIdx.x * 2 + 1] = fkey(b2);
    }
    if (t < 64) {
        u64 ts[TBLK];
        #pragma unroll
        for (int j = 0; j < TBLK; j++) ts[j] = 0ull;
        int bt = t >> 4, l = t & 15;
        #pragma unroll
        for (int w2 = 0; w2 < 4; w2++) {
            insert_key<TBLK>(ts, mrg[w2][bt][l][0]);
            insert_key<TBLK>(ts, mrg[w2][bt][l][1]);
        }
        #pragma unroll
        for (int j = 0; j < TBLK; j++)
            cand[((long long)blockIdx.x * 64 + t) * TBLK + j] = ts[j];
    }
}

// One block per batch: reduce min/max partials -> scale/zp (overlapped with
// candidate gather), per-thread gated top-16 over strided candidates,
// 8-level pairwise sorted-merge tree, exact fp32 rescore of top-16, top-5,
// softmax, weighted dequant row sum, @ Wv^T.
__global__ void k_finalize(const u64* __restrict__ cand, int nb2,
                           const float* __restrict__ mem, const float* __restrict__ aw,
                           const float* __restrict__ Wv, const unsigned* __restrict__ part,
                           const float* __restrict__ qkf, float* __restrict__ out) {
    __shared__ u64 lists[256][TRES];   // 32 KB
    __shared__ float qkr[64];
    __shared__ int exid[TRES];
    __shared__ u64 exkey[TRES];
    __shared__ float exsc[TRES];
    __shared__ float wsel[TOPK];
    __shared__ int isel[TOPK];
    __shared__ float su[64];
    __shared__ unsigned redmn[4], redmx[4];
    __shared__ float sscale[2];

    int t = threadIdx.x, b = blockIdx.x;
    int total = nb2 * TBLK;

    // min/max partial reduction (independent of candidate gather)
    unsigned mnk = 0xFFFFFFFFu, mxk = 0u;
    for (int i = t; i < nb2; i += 256) {
        unsigned a = part[2 * i], c = part[2 * i + 1];
        mnk = a < mnk ? a : mnk;
        mxk = c > mxk ? c : mxk;
    }
    #pragma unroll
    for (int o = 32; o > 0; o >>= 1) {
        unsigned am = __shfl_xor(mnk, o); mnk = am < mnk ? am : mnk;
        unsigned ax = __shfl_xor(mxk, o); mxk = ax > mxk ? ax : mxk;
    }
    int w4 = t >> 6;
    if ((t & 63) == 0) { redmn[w4] = mnk; redmx[w4] = mxk; }

    u64 loc[TRES];
    #pragma unroll
    for (int j = 0; j < TRES; j++) loc[j] = 0ull;
    for (int i = t; i < total; i += 256) {
        int blk = i / TBLK, j = i - blk * TBLK;
        insert_key<TRES>(loc, cand[((long long)blk * 64 + b) * TBLK + j]);
    }
    #pragma unroll
    for (int j = 0; j < TRES; j++) lists[t][j] = loc[j];
    if (t < 64) qkr[t] = qkf[b * 64 + t];
    __syncthreads();

    // idle thread finalizes scale/zp
    if (t == 255) {
        unsigned m0 = redmn[0], M0 = redmx[0];
        #pragma unroll
        for (int i = 1; i < 4; i++) {
            m0 = redmn[i] < m0 ? redmn[i] : m0;
            M0 = redmx[i] > M0 ? redmx[i] : M0;
        }
        float mnv = fkey_inv(m0), mxv = fkey_inv(M0);
        float scale = (mxv - mnv) / 255.0f;
        sscale[0] = scale;
        sscale[1] = -mnv / scale;
    }

    for (int s = 128; s > 0; s >>= 1) {
        if (t < s) {
            #pragma unroll
            for (int j = 0; j < TRES; j++) insert_key<TRES>(loc, lists[t + s][j]);
            #pragma unroll
            for (int j = 0; j < TRES; j++) lists[t][j] = loc[j];
        }
        __syncthreads();
    }
    if (t < TRES) {
        u64 k = lists[0][t];
        exid[t] = k ? (int)(~(unsigned)k) : 0;
    }
    __syncthreads();

    float scale = sscale[0], zp = sscale[1];

    // exact rescore (mirrors reference: divide, rint, fp32)
    int lane = t & 63, w = t >> 6;
    for (int i = 0; i < 4; i++) {
        int c = w * 4 + i;
        int idx = exid[c];
        float m = mem[(long long)idx * 64 + lane];
        float dq = (rintf(m / scale + zp) - zp) * scale;
        float p2 = dq * qkr[lane];
        for (int o = 32; o > 0; o >>= 1) p2 += __shfl_xor(p2, o);
        if (lane == 0) {
            float ex = p2 + aw[idx];
            exsc[c] = ex;
            exkey[c] = ((u64)fkey(ex) << 32) | (unsigned)(~(unsigned)idx);
        }
    }
    __syncthreads();

    if (t == 0) {
        u64 bnd = ~0ull;
        float ssel[TOPK];
        for (int p = 0; p < TOPK; p++) {
            u64 best = 0ull; int bc = 0;
            for (int c = 0; c < TRES; c++) {
                u64 k = exkey[c];
                if (k < bnd && k > best) { best = k; bc = c; }
            }
            bnd = best;
            ssel[p] = exsc[bc];
            isel[p] = exid[bc];
        }
        float Z = 0.f;
        for (int p = 0; p < TOPK; p++) { wsel[p] = expf(ssel[p] - ssel[0]); Z += wsel[p]; }
        for (int p = 0; p < TOPK; p++) wsel[p] /= Z;
    }
    __syncthreads();

    if (t < 64) {
        float u = 0.f;
        #pragma unroll
        for (int p = 0; p < TOPK; p++) {
            float m = mem[(long long)isel[p] * 64 + t];
            float dq = (rintf(m / scale + zp) - zp) * scale;
            u += wsel[p] * dq;
        }
        su[t] = u;
    }
    __syncthreads();
    if (t < 64) {
        float o = 0.f;
        #pragma unroll
        for (int e = 0; e < 64; e++) o += su[e] * Wv[t * 64 + e];
        out[b * 64 + t] = o;
    }
}

extern "C" void kernel_launch(void* const* d_in, const int* in_sizes, int n_in,
                              void* d_out, int out_size, void* d_ws, size_t ws_size,
                              hipStream_t stream) {
    const float* query = (const float*)d_in[0];
    const float* mem   = (const float*)d_in[1];
    const float* aw    = (const float*)d_in[2];
    const float* Wq    = (const float*)d_in[3];
    const float* Wk    = (const float*)d_in[4];
    const float* Wv    = (const float*)d_in[5];
    float* out = (float*)d_out;

    char* ws = (char*)d_ws;
    float* qkf     = (float*)(ws + OFF_QKF);
    unsigned short* qkb = (unsigned short*)(ws + OFF_QKB);
    unsigned* part = (unsigned*)(ws + OFF_MM);
    u64* cand = (u64*)(ws + OFF_CAND);

    int nb2 = NB2MAX;
    size_t need = (size_t)OFF_CAND + (size_t)nb2 * 64 * TBLK * 8;
    if (ws_size < need) {
        size_t avail = ws_size > OFF_CAND ? ws_size - OFF_CAND : 0;
        nb2 = (int)(avail / ((size_t)64 * TBLK * 8));
        if (nb2 < 8) nb2 = 8;
        if (nb2 > NB2MAX) nb2 = NB2MAX;
    }
    int waves = nb2 * 4;
    int wrows = ((NROWS + waves - 1) / waves + 15) / 16 * 16;  // 16-row multiple per wave

    k_qk<<<16, 256, 0, stream>>>(query, Wq, Wk, qkf, qkb);
    k_score_mm<<<nb2, 256, 0, stream>>>(mem, aw, qkb, cand, part, wrows);
    k_finalize<<<B, 256, 0, stream>>>(cand, nb2, mem, aw, Wv, part, qkf, out);
}